// Round 11
// baseline (112.805 us; speedup 1.0000x reference)
//
#include <hip/hip_runtime.h>

#define NTH 256
#define N_NODES 2048

typedef float f32x2 __attribute__((ext_vector_type(2)));

// Pair-packed split symmetrized coefficient tables (workspace floats).
// nu3: 83 pairs x 12 floats  {cA[q0],cB[q0], cA[q1],cB[q1], ...} (t=165 zero-pad)
// nu2: 23 pairs x 8 floats   (t=45 zero-pad)
// nu1: 9 x 2 floats (scalar)
#define G3A_OFF 0       // 83*12 = 996
#define G3B_OFF 996
#define G2A_OFF 1992    // 23*8 = 184
#define G2B_OFF 2176
#define G1A_OFF 2360    // 9*2 = 18
#define G1B_OFF 2378
#define TAB_FLOATS 2396

// compile-time multiset decode tables (fold to immediates after unroll)
struct Trip3Tab { unsigned short v[166]; };
constexpr Trip3Tab make_trip3() {
    Trip3Tab tt{};
    int c = 0;
    for (int i = 0; i < 9; i++)
        for (int j = i; j < 9; j++)
            for (int k = j; k < 9; k++)
                tt.v[c++] = (unsigned short)(i | (j << 4) | (k << 8));
    tt.v[165] = 0;   // pad (coeffs are zero)
    return tt;
}
__device__ constexpr Trip3Tab TRIP3 = make_trip3();

struct Trip2Tab { unsigned short v[46]; };
constexpr Trip2Tab make_trip2() {
    Trip2Tab tt{};
    int c = 0;
    for (int i = 0; i < 9; i++)
        for (int j = i; j < 9; j++)
            tt.v[c++] = (unsigned short)(i | (j << 4));
    tt.v[45] = 0;    // pad
    return tt;
}
__device__ constexpr Trip2Tab TRIP2 = make_trip2();

// ---------------- prep: build pair-packed split tables into global ws ----------------
__global__ void mace_prep(
    const float* __restrict__ b10, const float* __restrict__ b11,
    const float* __restrict__ b20, const float* __restrict__ b21,
    const float* __restrict__ b30, const float* __restrict__ b31,
    float* __restrict__ tab)
{
    const int tid = threadIdx.x;
    if (tid < 165) {
        int i = 0, j = 0, k = 0;
        {
            int c = 0;
            for (int ii = 0; ii < 9; ii++)
                for (int jj = ii; jj < 9; jj++)
                    for (int kk = jj; kk < 9; kk++) {
                        if (c == tid) { i = ii; j = jj; k = kk; }
                        c++;
                    }
        }
        float s[12];
        #pragma unroll
        for (int q = 0; q < 12; q++) s[q] = 0.f;
        auto add3 = [&](int a, int b, int c2) {
            int o30 = ((a * 9 + b) * 9 + c2) * 3;   // b30: (9,9,9,3,1)
            int o31 = o30 * 3;                      // b31: (9,9,9,3,3)
            #pragma unroll
            for (int q = 0; q < 3; q++) s[q] += b30[o30 + q];
            #pragma unroll
            for (int q = 0; q < 9; q++) s[3 + q] += b31[o31 + q];
        };
        if (i == j && j == k) { add3(i, j, k); }
        else if (i == j)      { add3(i, i, k); add3(i, k, i); add3(k, i, i); }
        else if (j == k)      { add3(i, j, j); add3(j, i, j); add3(j, j, i); }
        else { add3(i,j,k); add3(i,k,j); add3(j,i,k); add3(j,k,i); add3(k,i,j); add3(k,j,i); }
        const int p = tid >> 1, l = tid & 1;        // pair-interleaved write
        #pragma unroll
        for (int q = 0; q < 6; q++) {
            tab[G3A_OFF + p * 12 + 2 * q + l] = s[q];
            tab[G3B_OFF + p * 12 + 2 * q + l] = s[6 + q];
        }
    } else if (tid < 210) {
        int t = tid - 165;
        int i = 0, j = 0;
        {
            int c = 0;
            for (int ii = 0; ii < 9; ii++)
                for (int jj = ii; jj < 9; jj++) {
                    if (c == t) { i = ii; j = jj; }
                    c++;
                }
        }
        float s[8];
        #pragma unroll
        for (int q = 0; q < 8; q++) s[q] = 0.f;
        auto add2 = [&](int a, int b) {
            int o20 = (a * 9 + b) * 2;   // b20: (9,9,2,1)
            int o21 = o20 * 3;           // b21: (9,9,2,3)
            #pragma unroll
            for (int q = 0; q < 2; q++) s[q] += b20[o20 + q];
            #pragma unroll
            for (int q = 0; q < 6; q++) s[2 + q] += b21[o21 + q];
        };
        if (i == j) add2(i, i); else { add2(i, j); add2(j, i); }
        const int p = t >> 1, l = t & 1;
        #pragma unroll
        for (int q = 0; q < 4; q++) {
            tab[G2A_OFF + p * 8 + 2 * q + l] = s[q];
            tab[G2B_OFF + p * 8 + 2 * q + l] = s[4 + q];
        }
    } else if (tid < 219) {
        int a = tid - 210;
        tab[G1A_OFF + a * 2 + 0] = b10[a];           // b10: (9,1,1)
        tab[G1A_OFF + a * 2 + 1] = b11[a * 3 + 0];   // b11: (9,1,3)
        tab[G1B_OFF + a * 2 + 0] = b11[a * 3 + 1];
        tab[G1B_OFF + a * 2 + 1] = b11[a * 3 + 2];
    } else if (tid == 219) {
        // zero the pad lanes (t=165 for nu3, t=45 for nu2)
        #pragma unroll
        for (int q = 0; q < 6; q++) {
            tab[G3A_OFF + 82 * 12 + 2 * q + 1] = 0.f;
            tab[G3B_OFF + 82 * 12 + 2 * q + 1] = 0.f;
        }
        #pragma unroll
        for (int q = 0; q < 4; q++) {
            tab[G2A_OFF + 22 * 8 + 2 * q + 1] = 0.f;
            tab[G2B_OFF + 22 * 8 + 2 * q + 1] = 0.f;
        }
    }
}

// ---------------- main: one block per node, q-split, pair-packed pk-FMA ----------------
// Structure = round 5/7/10 (best). Change: multisets processed in PAIRS with the
// table pair-interleaved, so each coefficient f32x2 is one contiguous SGPR-pair
// s_load and each inner op is v_pk_fma_f32 (VOP3P, 1 SGPR src legal). Halves both
// the inner VALU instruction count and the number of coefficient records (drains).
// Falls back to 2 scalar FMAs if the backend declines to pack (flat, not worse).
// Working set stays in SGPRs (round-2/9 lesson: VGPR growth = spill cliff).
__global__ __launch_bounds__(NTH, 2) void mace_sc_kernel(
    const float* __restrict__ nf, const int* __restrict__ spec,
    const float* __restrict__ w10, const float* __restrict__ w11,
    const float* __restrict__ w20, const float* __restrict__ w21,
    const float* __restrict__ w30, const float* __restrict__ w31,
    const float* __restrict__ tab, float* __restrict__ out)
{
    __shared__ float part[4][128];   // half-B partial acc, [p][m]

    const int node = blockIdx.x;
    const int tid  = threadIdx.x;
    const int m    = tid & 127;
    // wave-uniform half index, pinned to SGPR (round-4 lesson)
    const int hs   = __builtin_amdgcn_readfirstlane(tid >> 7);

    const float* nfp = nf + node * 1152;
    float f[9];
    f[0] = nfp[m];                                                  // 0e block
    #pragma unroll
    for (int j = 0; j < 3; j++) f[1 + j] = nfp[128 + m * 3 + j];    // 1o block
    #pragma unroll
    for (int j = 0; j < 5; j++) f[4 + j] = nfp[512 + m * 5 + j];    // 2e block

    const int z = spec[node];                   // block-uniform -> scalar

    float acc[4];
    #pragma unroll
    for (int p = 0; p < 4; p++) acc[p] = 0.f;

    // ---- nu = 3 ----  (83 pairs, packed FMA)
    {
        const f32x2* g3 = (const f32x2*)(tab + (hs ? G3B_OFF : G3A_OFF));
        f32x2 a2[6];
        #pragma unroll
        for (int q = 0; q < 6; q++) a2[q] = (f32x2)(0.f);

        #pragma unroll
        for (int p = 0; p < 83; p++) {
            const unsigned ta = TRIP3.v[2 * p];       // folds to immediate
            const unsigned tb = TRIP3.v[2 * p + 1];
            f32x2 mm;
            mm.x = f[ta & 15] * f[(ta >> 4) & 15] * f[(ta >> 8) & 15];
            mm.y = f[tb & 15] * f[(tb >> 4) & 15] * f[(tb >> 8) & 15];
            #pragma unroll
            for (int q = 0; q < 6; q++)
                a2[q] = __builtin_elementwise_fma(g3[p * 6 + q], mm, a2[q]);
        }
        float t3[6];
        #pragma unroll
        for (int q = 0; q < 6; q++) t3[q] = a2[q].x + a2[q].y;

        if (hs == 0) {
            const float* w30z = w30 + z * 384;   // (10,3,128)
            const float* w31z = w31 + z * 384;
            #pragma unroll
            for (int s = 0; s < 3; s++)
                acc[0] = fmaf(w30z[s * 128 + m], t3[s], acc[0]);
            const float wu = w31z[m];            // s = 0
            acc[1] = fmaf(wu, t3[3], acc[1]);
            acc[2] = fmaf(wu, t3[4], acc[2]);
            acc[3] = fmaf(wu, t3[5], acc[3]);
        } else {
            const float* w31z = w31 + z * 384;
            const float wu1 = w31z[128 + m];     // s = 1
            const float wu2 = w31z[256 + m];     // s = 2
            acc[1] = fmaf(wu1, t3[0], acc[1]);
            acc[2] = fmaf(wu1, t3[1], acc[2]);
            acc[3] = fmaf(wu1, t3[2], acc[3]);
            acc[1] = fmaf(wu2, t3[3], acc[1]);
            acc[2] = fmaf(wu2, t3[4], acc[2]);
            acc[3] = fmaf(wu2, t3[5], acc[3]);
        }
    }

    // ---- nu = 2 ----  (23 pairs, packed FMA)
    {
        const f32x2* g2 = (const f32x2*)(tab + (hs ? G2B_OFF : G2A_OFF));
        f32x2 b2[4];
        #pragma unroll
        for (int q = 0; q < 4; q++) b2[q] = (f32x2)(0.f);

        #pragma unroll
        for (int p = 0; p < 23; p++) {
            const unsigned ta = TRIP2.v[2 * p];
            const unsigned tb = TRIP2.v[2 * p + 1];
            f32x2 mm;
            mm.x = f[ta & 15] * f[(ta >> 4) & 15];
            mm.y = f[tb & 15] * f[(tb >> 4) & 15];
            #pragma unroll
            for (int q = 0; q < 4; q++)
                b2[q] = __builtin_elementwise_fma(g2[p * 4 + q], mm, b2[q]);
        }
        float t2[4];
        #pragma unroll
        for (int q = 0; q < 4; q++) t2[q] = b2[q].x + b2[q].y;

        if (hs == 0) {
            const float* w20z = w20 + z * 256;   // (10,2,128)
            const float* w21z = w21 + z * 256;
            acc[0] = fmaf(w20z[m],       t2[0], acc[0]);
            acc[0] = fmaf(w20z[128 + m], t2[1], acc[0]);
            const float wu = w21z[m];            // s = 0 -> p0,p1
            acc[1] = fmaf(wu, t2[2], acc[1]);
            acc[2] = fmaf(wu, t2[3], acc[2]);
        } else {
            const float* w21z = w21 + z * 256;
            const float wu0 = w21z[m];           // s = 0 -> p2
            acc[3] = fmaf(wu0, t2[0], acc[3]);
            const float wu1 = w21z[128 + m];     // s = 1 -> p0..2
            acc[1] = fmaf(wu1, t2[1], acc[1]);
            acc[2] = fmaf(wu1, t2[2], acc[2]);
            acc[3] = fmaf(wu1, t2[3], acc[3]);
        }
    }

    // ---- nu = 1 ----  (scalar, tiny)
    {
        const float* g1 = tab + (hs ? G1B_OFF : G1A_OFF);
        float t1[2];
        t1[0] = 0.f; t1[1] = 0.f;
        #pragma unroll
        for (int a = 0; a < 9; a++) {
            t1[0] = fmaf(g1[a * 2 + 0], f[a], t1[0]);
            t1[1] = fmaf(g1[a * 2 + 1], f[a], t1[1]);
        }
        if (hs == 0) {
            acc[0] = fmaf(w10[z * 128 + m], t1[0], acc[0]);
            acc[1] = fmaf(w11[z * 128 + m], t1[1], acc[1]);
        } else {
            const float wu = w11[z * 128 + m];
            acc[2] = fmaf(wu, t1[0], acc[2]);
            acc[3] = fmaf(wu, t1[1], acc[3]);
        }
    }

    // ---- combine halves via LDS, store from half-A waves ----
    if (hs == 1) {
        #pragma unroll
        for (int p = 0; p < 4; p++) part[p][m] = acc[p];
    }
    __syncthreads();
    if (hs == 0) {
        #pragma unroll
        for (int p = 0; p < 4; p++) acc[p] += part[p][m];
        float* op = out + node * 512;
        op[m] = acc[0];
        #pragma unroll
        for (int p = 0; p < 3; p++) op[128 + m * 3 + p] = acc[1 + p];
    }
}

extern "C" void kernel_launch(void* const* d_in, const int* in_sizes, int n_in,
                              void* d_out, int out_size, void* d_ws, size_t ws_size,
                              hipStream_t stream) {
    // setup_inputs() dict order is INTERLEAVED: node_feats, species,
    // b10, w10, b11, w11, b20, w20, b21, w21, b30, w30, b31, w31
    const float* nf  = (const float*)d_in[0];
    const int* spec  = (const int*)d_in[1];
    const float* b10 = (const float*)d_in[2];
    const float* w10 = (const float*)d_in[3];
    const float* b11 = (const float*)d_in[4];
    const float* w11 = (const float*)d_in[5];
    const float* b20 = (const float*)d_in[6];
    const float* w20 = (const float*)d_in[7];
    const float* b21 = (const float*)d_in[8];
    const float* w21 = (const float*)d_in[9];
    const float* b30 = (const float*)d_in[10];
    const float* w30 = (const float*)d_in[11];
    const float* b31 = (const float*)d_in[12];
    const float* w31 = (const float*)d_in[13];
    float* out = (float*)d_out;
    float* tab = (float*)d_ws;                 // needs TAB_FLOATS*4 = 9.6 KB

    mace_prep<<<1, 256, 0, stream>>>(b10, b11, b20, b21, b30, b31, tab);

    // one block per node; waves 0-1 = half A, waves 2-3 = half B
    mace_sc_kernel<<<N_NODES, NTH, 0, stream>>>(
        nf, spec, w10, w11, w20, w21, w30, w31, tab, out);
}